// Round 9
// baseline (314.245 us; speedup 1.0000x reference)
//
#include <hip/hip_runtime.h>

#define NEG_SLOPE 0.2f
#define NBUCK 256

// ===========================================================================
// Register-blocked GEMM: out[N,64] = x[N,64] @ W[64,64]
// 64x64 tile per block; 256 threads; 4x4 outputs/thread.
// WANT_ALPHA: also alpha_s/alpha_d = (out * a).sum(-1) via 16-lane reduce.
// DO_HIST: blocks 0..255 additionally histogram edge dst>>8 into bhist.
// ===========================================================================
template <bool WANT_ALPHA, bool DO_HIST>
__global__ __launch_bounds__(256) void gemm64(
    const float* __restrict__ x, const float* __restrict__ W,
    const float* __restrict__ a_src, const float* __restrict__ a_dst,
    float* __restrict__ out, float* __restrict__ alpha_s,
    float* __restrict__ alpha_d, int N,
    const int* __restrict__ ei, int E, int* __restrict__ bhist)
{
    __shared__ float Xs[64][68];   // +4 pad: column reads 2-way max (free)
    __shared__ float Ws[64][64];
    __shared__ int   hsh[NBUCK];

    const int row0 = blockIdx.x * 64;

    for (int i = threadIdx.x; i < 1024; i += 256)
        ((float4*)Ws)[i] = ((const float4*)W)[i];
    for (int i = threadIdx.x; i < 1024; i += 256) {
        int r = i >> 4, c4 = (i & 15) * 4;
        float4 v = {0.f, 0.f, 0.f, 0.f};
        if (row0 + r < N) v = *(const float4*)&x[(size_t)(row0 + r) * 64 + c4];
        *(float4*)&Xs[r][c4] = v;
    }
    if (DO_HIST && blockIdx.x < 256) hsh[threadIdx.x] = 0;
    __syncthreads();

    const int tx = threadIdx.x & 15;
    const int ty = threadIdx.x >> 4;

    float acc[4][4] = {{0.f,0.f,0.f,0.f},{0.f,0.f,0.f,0.f},
                       {0.f,0.f,0.f,0.f},{0.f,0.f,0.f,0.f}};

#pragma unroll 8
    for (int k = 0; k < 64; ++k) {
        const float4 wv = *(const float4*)&Ws[k][tx * 4];
        const float x0 = Xs[ty * 4 + 0][k];
        const float x1 = Xs[ty * 4 + 1][k];
        const float x2 = Xs[ty * 4 + 2][k];
        const float x3 = Xs[ty * 4 + 3][k];
        acc[0][0] += x0 * wv.x; acc[0][1] += x0 * wv.y;
        acc[0][2] += x0 * wv.z; acc[0][3] += x0 * wv.w;
        acc[1][0] += x1 * wv.x; acc[1][1] += x1 * wv.y;
        acc[1][2] += x1 * wv.z; acc[1][3] += x1 * wv.w;
        acc[2][0] += x2 * wv.x; acc[2][1] += x2 * wv.y;
        acc[2][2] += x2 * wv.z; acc[2][3] += x2 * wv.w;
        acc[3][0] += x3 * wv.x; acc[3][1] += x3 * wv.y;
        acc[3][2] += x3 * wv.z; acc[3][3] += x3 * wv.w;
    }

#pragma unroll
    for (int i = 0; i < 4; ++i) {
        const int r = row0 + ty * 4 + i;
        if (r < N) {
            float4 o = {acc[i][0], acc[i][1], acc[i][2], acc[i][3]};
            *(float4*)&out[(size_t)r * 64 + tx * 4] = o;
        }
    }

    if (WANT_ALPHA) {
        const float4 asv = *(const float4*)&a_src[tx * 4];
        const float4 adv = *(const float4*)&a_dst[tx * 4];
#pragma unroll
        for (int i = 0; i < 4; ++i) {
            float s = acc[i][0]*asv.x + acc[i][1]*asv.y
                    + acc[i][2]*asv.z + acc[i][3]*asv.w;
            float d = acc[i][0]*adv.x + acc[i][1]*adv.y
                    + acc[i][2]*adv.z + acc[i][3]*adv.w;
#pragma unroll
            for (int off = 1; off < 16; off <<= 1) {
                s += __shfl_xor(s, off, 16);
                d += __shfl_xor(d, off, 16);
            }
            const int r = row0 + ty * 4 + i;
            if (tx == 0 && r < N) { alpha_s[r] = s; alpha_d[r] = d; }
        }
    }

    // fused CSR pass 0: bucket histogram (256 blocks, slice each)
    if (DO_HIST && blockIdx.x < 256) {
        __syncthreads();
        for (int e = blockIdx.x * 256 + threadIdx.x; e < E; e += 256 * 256)
            atomicAdd(&hsh[((unsigned)ei[E + e]) >> 8], 1);
        __syncthreads();
        if (hsh[threadIdx.x]) atomicAdd(&bhist[threadIdx.x], hsh[threadIdx.x]);
    }
}

// ===========================================================================
// Fused MLP head: out[N,32] = relu(X @ W1 + b1) @ W2 + b2
// ===========================================================================
__global__ __launch_bounds__(256) void gemm_head(
    const float* __restrict__ X, const float* __restrict__ W1,
    const float* __restrict__ b1, const float* __restrict__ W2,
    const float* __restrict__ b2, float* __restrict__ out, int N)
{
    __shared__ float Xs[64][68];
    __shared__ float W1s[64][64];
    __shared__ float W2s[64][32];

    const int row0 = blockIdx.x * 64;

    for (int i = threadIdx.x; i < 1024; i += 256)
        ((float4*)W1s)[i] = ((const float4*)W1)[i];
    for (int i = threadIdx.x; i < 512; i += 256)
        ((float4*)W2s)[i] = ((const float4*)W2)[i];
    for (int i = threadIdx.x; i < 1024; i += 256) {
        int r = i >> 4, c4 = (i & 15) * 4;
        float4 v = {0.f, 0.f, 0.f, 0.f};
        if (row0 + r < N) v = *(const float4*)&X[(size_t)(row0 + r) * 64 + c4];
        *(float4*)&Xs[r][c4] = v;
    }
    __syncthreads();

    const int tx = threadIdx.x & 15;
    const int ty = threadIdx.x >> 4;

    float acc[4][4] = {{0,0,0,0},{0,0,0,0},{0,0,0,0},{0,0,0,0}};
#pragma unroll 8
    for (int k = 0; k < 64; ++k) {
        const float4 wv = *(const float4*)&W1s[k][tx * 4];
        const float x0 = Xs[ty * 4 + 0][k];
        const float x1 = Xs[ty * 4 + 1][k];
        const float x2 = Xs[ty * 4 + 2][k];
        const float x3 = Xs[ty * 4 + 3][k];
        acc[0][0] += x0 * wv.x; acc[0][1] += x0 * wv.y;
        acc[0][2] += x0 * wv.z; acc[0][3] += x0 * wv.w;
        acc[1][0] += x1 * wv.x; acc[1][1] += x1 * wv.y;
        acc[1][2] += x1 * wv.z; acc[1][3] += x1 * wv.w;
        acc[2][0] += x2 * wv.x; acc[2][1] += x2 * wv.y;
        acc[2][2] += x2 * wv.z; acc[2][3] += x2 * wv.w;
        acc[3][0] += x3 * wv.x; acc[3][1] += x3 * wv.y;
        acc[3][2] += x3 * wv.z; acc[3][3] += x3 * wv.w;
    }

    const float4 bv = *(const float4*)&b1[tx * 4];
    __syncthreads();   // done reading Xs as X
#pragma unroll
    for (int i = 0; i < 4; ++i) {
        Xs[ty * 4 + i][tx * 4 + 0] = fmaxf(acc[i][0] + bv.x, 0.f);
        Xs[ty * 4 + i][tx * 4 + 1] = fmaxf(acc[i][1] + bv.y, 0.f);
        Xs[ty * 4 + i][tx * 4 + 2] = fmaxf(acc[i][2] + bv.z, 0.f);
        Xs[ty * 4 + i][tx * 4 + 3] = fmaxf(acc[i][3] + bv.w, 0.f);
    }
    __syncthreads();

    float a2[4][2] = {{0,0},{0,0},{0,0},{0,0}};
#pragma unroll 8
    for (int k = 0; k < 64; ++k) {
        const float2 wv = *(const float2*)&W2s[k][tx * 2];
        const float t0 = Xs[ty * 4 + 0][k];
        const float t1 = Xs[ty * 4 + 1][k];
        const float t2 = Xs[ty * 4 + 2][k];
        const float t3 = Xs[ty * 4 + 3][k];
        a2[0][0] += t0 * wv.x; a2[0][1] += t0 * wv.y;
        a2[1][0] += t1 * wv.x; a2[1][1] += t1 * wv.y;
        a2[2][0] += t2 * wv.x; a2[2][1] += t2 * wv.y;
        a2[3][0] += t3 * wv.x; a2[3][1] += t3 * wv.y;
    }
    const float2 b2v = *(const float2*)&b2[tx * 2];
#pragma unroll
    for (int i = 0; i < 4; ++i) {
        const int r = row0 + ty * 4 + i;
        if (r < N) {
            float2 o;
            o.x = a2[i][0] + b2v.x;
            o.y = a2[i][1] + b2v.y;
            *(float2*)&out[(size_t)r * 32 + tx * 2] = o;
        }
    }
}

// ===========================================================================
// CSR build: coarse partition -> in-bucket scatter (hist fused into gemm1)
// ===========================================================================
#define PC_EPT 8
#define PC_TILE 2048
__global__ __launch_bounds__(256) void partition_coarse(
    const int* __restrict__ ei, int E, const int* __restrict__ bhist,
    int* __restrict__ gcurs, int* __restrict__ pairs)
{
    __shared__ int sc[NBUCK];
    __shared__ int hist[NBUCK];
    __shared__ int base[NBUCK];
    const int t = threadIdx.x;

    const int bh = bhist[t];
    sc[t] = bh; __syncthreads();
    for (int off = 1; off < 256; off <<= 1) {
        int v = sc[t];
        if (t >= off) v += sc[t - off];
        __syncthreads(); sc[t] = v; __syncthreads();
    }
    const int bbase = sc[t] - bh;
    hist[t] = 0;
    __syncthreads();

    const int tile0 = blockIdx.x * PC_TILE;
    int sv[PC_EPT], dv[PC_EPT], rk[PC_EPT];
#pragma unroll
    for (int i = 0; i < PC_EPT; ++i) {
        const int e = tile0 + i * 256 + t;
        if (e < E) {
            sv[i] = ei[e];
            dv[i] = ei[E + e];
            rk[i] = atomicAdd(&hist[dv[i] >> 8], 1);
        } else dv[i] = -1;
    }
    __syncthreads();
    if (hist[t] > 0) base[t] = bbase + atomicAdd(&gcurs[t], hist[t]);
    __syncthreads();
#pragma unroll
    for (int i = 0; i < PC_EPT; ++i) {
        if (dv[i] >= 0) {
            const int b = dv[i] >> 8;
            pairs[base[b] + rk[i]] = sv[i] | ((dv[i] & 255) << 16);
        }
    }
}

__global__ __launch_bounds__(256) void fine_scatter(
    const int* __restrict__ bhist, const int* __restrict__ pairs,
    int N, int E, int* __restrict__ row_off, int* __restrict__ csr_src)
{
    __shared__ int sc[NBUCK];
    __shared__ int cnt[NBUCK];
    __shared__ int cur[NBUCK];
    const int t = threadIdx.x, b = blockIdx.x;

    const int bh = bhist[t];
    sc[t] = bh; __syncthreads();
    for (int off = 1; off < 256; off <<= 1) {
        int v = sc[t];
        if (t >= off) v += sc[t - off];
        __syncthreads(); sc[t] = v; __syncthreads();
    }
    sc[t] -= bh;
    cnt[t] = 0;
    __syncthreads();

    const int sb = sc[b];
    const int se = sb + bhist[b];

    for (int p = sb + t; p < se; p += 256)
        atomicAdd(&cnt[pairs[p] >> 16], 1);
    __syncthreads();

    const int c = cnt[t];
    cur[t] = c; __syncthreads();
    for (int off = 1; off < 256; off <<= 1) {
        int v = cur[t];
        if (t >= off) v += cur[t - off];
        __syncthreads(); cur[t] = v; __syncthreads();
    }
    const int node_off = sb + cur[t] - c;
    __syncthreads();
    cur[t] = node_off;
    const int n = b * 256 + t;
    if (n < N) row_off[n] = node_off;
    if (b == gridDim.x - 1 && t == 0) row_off[N] = E;
    __syncthreads();

    for (int p = sb + t; p < se; p += 256) {
        const int v = pairs[p];
        const int pos = atomicAdd(&cur[v >> 16], 1);
        csr_src[pos] = v & 0xFFFF;
    }
}

// ===========================================================================
// GAT aggregation v6 — COLUMN-SLICED for per-XCD L2 residency.
// 4 slices x 16 columns: in slice k every block touches only
// h[:, 16k..16k+16) = 3.2 MB < 4 MB XCD-L2. Slice = slow block index, so
// the CP phases slices roughly sequentially. Per wave: one dst node,
// 16 edge-groups x 4 lanes (64B gather/edge/slice, 16-deep queue).
// No-max softmax (shift-invariance, |e| << 88); den recomputed identically
// per slice; slices write disjoint column ranges of X.
// ===========================================================================
__global__ __launch_bounds__(256) void gat_aggregate_sliced(
    const int* __restrict__ row_off, const int* __restrict__ csr_src,
    const float* __restrict__ h, const float* __restrict__ as,
    const float* __restrict__ ad, const float* __restrict__ bias,
    float* __restrict__ out, int N, int nchunks)
{
    const int slice = blockIdx.x / nchunks;          // 0..3 (slow index)
    const int chunk = blockIdx.x % nchunks;
    const int d     = chunk * 4 + (threadIdx.x >> 6); // one dst per wave
    if (d >= N) return;

    const int lane = threadIdx.x & 63;
    const int g    = lane >> 2;                      // edge group 0..15
    const int gl   = lane & 3;                       // cols: slice*16+gl*4 ..+3
    const int col0 = slice * 16 + gl * 4;

    const int beg = row_off[d], end = row_off[d + 1];
    const float add = ad[d];

    float  den = 0.f;
    float4 acc = {0.f, 0.f, 0.f, 0.f};

    // prefetch src one 16-edge chunk ahead
    int sp = (beg + g < end) ? csr_src[beg + g] : 0;

    for (int e0 = beg; e0 < end; e0 += 16) {
        const bool valid = (e0 + g < end);
        const int  s     = sp;
        sp = (e0 + 16 + g < end) ? csr_src[e0 + 16 + g] : 0;

        const float  av = as[s];
        const float4 hv = *(const float4*)&h[(size_t)s * 64 + col0];

        float ev = av + add;
        ev = (ev >= 0.f) ? ev : NEG_SLOPE * ev;
        const float w = valid ? __expf(ev) : 0.f;

        den += w;
        acc.x += w * hv.x; acc.y += w * hv.y;
        acc.z += w * hv.z; acc.w += w * hv.w;
    }

    // reduce the 16 edge-groups (lanes differ in bits 2..5)
#pragma unroll
    for (int off = 4; off <= 32; off <<= 1) {
        acc.x += __shfl_xor(acc.x, off, 64);
        acc.y += __shfl_xor(acc.y, off, 64);
        acc.z += __shfl_xor(acc.z, off, 64);
        acc.w += __shfl_xor(acc.w, off, 64);
        den   += __shfl_xor(den,   off, 64);
    }

    if (g == 0) {
        const float4 bvv = *(const float4*)&bias[col0];
        const float inv = (den > 0.f) ? (1.f / den) : 0.f;
        float4 o;
        o.x = fmaxf(acc.x * inv + bvv.x, 0.f);
        o.y = fmaxf(acc.y * inv + bvv.y, 0.f);
        o.z = fmaxf(acc.z * inv + bvv.z, 0.f);
        o.w = fmaxf(acc.w * inv + bvv.w, 0.f);
        *(float4*)&out[(size_t)d * 64 + col0] = o;
    }
}

extern "C" void kernel_launch(void* const* d_in, const int* in_sizes, int n_in,
                              void* d_out, int out_size, void* d_ws, size_t ws_size,
                              hipStream_t stream)
{
    const float* x  = (const float*)d_in[0];
    const int*   ei = (const int*)d_in[1];
    const float* W[3]    = {(const float*)d_in[2], (const float*)d_in[6],  (const float*)d_in[10]};
    const float* asrc[3] = {(const float*)d_in[3], (const float*)d_in[7],  (const float*)d_in[11]};
    const float* adst[3] = {(const float*)d_in[4], (const float*)d_in[8],  (const float*)d_in[12]};
    const float* bia[3]  = {(const float*)d_in[5], (const float*)d_in[9],  (const float*)d_in[13]};
    const float* lin1W = (const float*)d_in[14];
    const float* lin1b = (const float*)d_in[15];
    const float* lin2W = (const float*)d_in[16];
    const float* lin2b = (const float*)d_in[17];

    const int N = in_sizes[0] / 64;
    const int E = in_sizes[1] / 2;
    const int B = (N + 255) / 256;            // coarse buckets (<=256)

    // workspace layout
    float* X       = (float*)d_ws;            // N*64
    float* H       = X + (size_t)N * 64;      // N*64
    float* AS      = H + (size_t)N * 64;      // N
    float* AD      = AS + N;                  // N
    int*   row_off = (int*)(AD + N);          // N+1
    int*   csr_src = row_off + (N + 1);       // E
    int*   bhist   = csr_src + E;             // 256
    int*   gcurs   = bhist + 256;             // 256
    int*   pairs   = gcurs + 256;             // E

    const int g64_grid = (N + 63) / 64;
    const int nchunks  = (N + 3) / 4;
    const int agg_grid = 4 * nchunks;         // 4 column slices
    const int pc_grid  = (E + PC_TILE - 1) / PC_TILE;

    hipMemsetAsync(bhist, 0, 512 * sizeof(int), stream);

    // ---- layer 1 GEMM (+ fused bucket histogram) ----
    gemm64<true, true><<<g64_grid, 256, 0, stream>>>(
        x, W[0], asrc[0], adst[0], H, AS, AD, N, ei, E, bhist);

    // ---- CSR build ----
    partition_coarse<<<pc_grid, 256, 0, stream>>>(ei, E, bhist, gcurs, pairs);
    fine_scatter<<<B, 256, 0, stream>>>(bhist, pairs, N, E, row_off, csr_src);

    // ---- layer 1 aggregate ----
    gat_aggregate_sliced<<<agg_grid, 256, 0, stream>>>(
        row_off, csr_src, H, AS, AD, bia[0], X, N, nchunks);

    // ---- layers 2,3 ----
    for (int l = 1; l < 3; ++l) {
        gemm64<true, false><<<g64_grid, 256, 0, stream>>>(
            X, W[l], asrc[l], adst[l], H, AS, AD, N, nullptr, 0, nullptr);
        gat_aggregate_sliced<<<agg_grid, 256, 0, stream>>>(
            row_off, csr_src, H, AS, AD, bia[l], X, N, nchunks);
    }

    // ---- fused MLP head ----
    gemm_head<<<g64_grid, 256, 0, stream>>>(
        X, lin1W, lin1b, lin2W, lin2b, (float*)d_out, N);
}

// Round 10
// 248.615 us; speedup vs baseline: 1.2640x; 1.2640x over previous
//
#include <hip/hip_runtime.h>

#define NEG_SLOPE 0.2f
#define NBUCK 256

// ===========================================================================
// Register-blocked GEMM: out[N,64] = x[N,64] @ W[64,64]
// 64x64 tile per block; 256 threads; 4x4 outputs/thread.
// Inner loop k-blocked by 4: all LDS reads are ds_read_b128 (Xs row stride
// 68 floats = 272 B, 16B-aligned at col multiples of 4). k-order preserved
// -> bitwise-identical accumulation vs scalar version.
// WANT_ALPHA: also alpha_s/alpha_d = (out * a).sum(-1) via 16-lane reduce.
// DO_HIST: blocks 0..255 additionally histogram edge dst>>8 into bhist.
// ===========================================================================
template <bool WANT_ALPHA, bool DO_HIST>
__global__ __launch_bounds__(256) void gemm64(
    const float* __restrict__ x, const float* __restrict__ W,
    const float* __restrict__ a_src, const float* __restrict__ a_dst,
    float* __restrict__ out, float* __restrict__ alpha_s,
    float* __restrict__ alpha_d, int N,
    const int* __restrict__ ei, int E, int* __restrict__ bhist)
{
    __shared__ float Xs[64][68];   // +4 pad
    __shared__ float Ws[64][64];
    __shared__ int   hsh[NBUCK];

    const int row0 = blockIdx.x * 64;

    for (int i = threadIdx.x; i < 1024; i += 256)
        ((float4*)Ws)[i] = ((const float4*)W)[i];
    for (int i = threadIdx.x; i < 1024; i += 256) {
        int r = i >> 4, c4 = (i & 15) * 4;
        float4 v = {0.f, 0.f, 0.f, 0.f};
        if (row0 + r < N) v = *(const float4*)&x[(size_t)(row0 + r) * 64 + c4];
        *(float4*)&Xs[r][c4] = v;
    }
    if (DO_HIST && blockIdx.x < 256) hsh[threadIdx.x] = 0;
    __syncthreads();

    const int tx = threadIdx.x & 15;
    const int ty = threadIdx.x >> 4;

    float acc[4][4] = {{0.f,0.f,0.f,0.f},{0.f,0.f,0.f,0.f},
                       {0.f,0.f,0.f,0.f},{0.f,0.f,0.f,0.f}};

#pragma unroll
    for (int k4 = 0; k4 < 16; ++k4) {
        // one b128 per output-row: Xs[ty*4+i][4k4 .. 4k4+3]
        const float4 xr0 = *(const float4*)&Xs[ty * 4 + 0][k4 * 4];
        const float4 xr1 = *(const float4*)&Xs[ty * 4 + 1][k4 * 4];
        const float4 xr2 = *(const float4*)&Xs[ty * 4 + 2][k4 * 4];
        const float4 xr3 = *(const float4*)&Xs[ty * 4 + 3][k4 * 4];
#pragma unroll
        for (int kk = 0; kk < 4; ++kk) {
            const float4 wv = *(const float4*)&Ws[k4 * 4 + kk][tx * 4];
            const float x0 = (&xr0.x)[kk];
            const float x1 = (&xr1.x)[kk];
            const float x2 = (&xr2.x)[kk];
            const float x3 = (&xr3.x)[kk];
            acc[0][0] += x0 * wv.x; acc[0][1] += x0 * wv.y;
            acc[0][2] += x0 * wv.z; acc[0][3] += x0 * wv.w;
            acc[1][0] += x1 * wv.x; acc[1][1] += x1 * wv.y;
            acc[1][2] += x1 * wv.z; acc[1][3] += x1 * wv.w;
            acc[2][0] += x2 * wv.x; acc[2][1] += x2 * wv.y;
            acc[2][2] += x2 * wv.z; acc[2][3] += x2 * wv.w;
            acc[3][0] += x3 * wv.x; acc[3][1] += x3 * wv.y;
            acc[3][2] += x3 * wv.z; acc[3][3] += x3 * wv.w;
        }
    }

#pragma unroll
    for (int i = 0; i < 4; ++i) {
        const int r = row0 + ty * 4 + i;
        if (r < N) {
            float4 o = {acc[i][0], acc[i][1], acc[i][2], acc[i][3]};
            *(float4*)&out[(size_t)r * 64 + tx * 4] = o;
        }
    }

    if (WANT_ALPHA) {
        const float4 asv = *(const float4*)&a_src[tx * 4];
        const float4 adv = *(const float4*)&a_dst[tx * 4];
#pragma unroll
        for (int i = 0; i < 4; ++i) {
            float s = acc[i][0]*asv.x + acc[i][1]*asv.y
                    + acc[i][2]*asv.z + acc[i][3]*asv.w;
            float d = acc[i][0]*adv.x + acc[i][1]*adv.y
                    + acc[i][2]*adv.z + acc[i][3]*adv.w;
#pragma unroll
            for (int off = 1; off < 16; off <<= 1) {
                s += __shfl_xor(s, off, 16);
                d += __shfl_xor(d, off, 16);
            }
            const int r = row0 + ty * 4 + i;
            if (tx == 0 && r < N) { alpha_s[r] = s; alpha_d[r] = d; }
        }
    }

    // fused CSR pass 0: bucket histogram (256 blocks, slice each)
    if (DO_HIST && blockIdx.x < 256) {
        __syncthreads();
        for (int e = blockIdx.x * 256 + threadIdx.x; e < E; e += 256 * 256)
            atomicAdd(&hsh[((unsigned)ei[E + e]) >> 8], 1);
        __syncthreads();
        if (hsh[threadIdx.x]) atomicAdd(&bhist[threadIdx.x], hsh[threadIdx.x]);
    }
}

// ===========================================================================
// Fused MLP head: out[N,32] = relu(X @ W1 + b1) @ W2 + b2
// ===========================================================================
__global__ __launch_bounds__(256) void gemm_head(
    const float* __restrict__ X, const float* __restrict__ W1,
    const float* __restrict__ b1, const float* __restrict__ W2,
    const float* __restrict__ b2, float* __restrict__ out, int N)
{
    __shared__ float Xs[64][68];
    __shared__ float W1s[64][64];
    __shared__ float W2s[64][32];

    const int row0 = blockIdx.x * 64;

    for (int i = threadIdx.x; i < 1024; i += 256)
        ((float4*)W1s)[i] = ((const float4*)W1)[i];
    for (int i = threadIdx.x; i < 512; i += 256)
        ((float4*)W2s)[i] = ((const float4*)W2)[i];
    for (int i = threadIdx.x; i < 1024; i += 256) {
        int r = i >> 4, c4 = (i & 15) * 4;
        float4 v = {0.f, 0.f, 0.f, 0.f};
        if (row0 + r < N) v = *(const float4*)&X[(size_t)(row0 + r) * 64 + c4];
        *(float4*)&Xs[r][c4] = v;
    }
    __syncthreads();

    const int tx = threadIdx.x & 15;
    const int ty = threadIdx.x >> 4;

    float acc[4][4] = {{0,0,0,0},{0,0,0,0},{0,0,0,0},{0,0,0,0}};
#pragma unroll
    for (int k4 = 0; k4 < 16; ++k4) {
        const float4 xr0 = *(const float4*)&Xs[ty * 4 + 0][k4 * 4];
        const float4 xr1 = *(const float4*)&Xs[ty * 4 + 1][k4 * 4];
        const float4 xr2 = *(const float4*)&Xs[ty * 4 + 2][k4 * 4];
        const float4 xr3 = *(const float4*)&Xs[ty * 4 + 3][k4 * 4];
#pragma unroll
        for (int kk = 0; kk < 4; ++kk) {
            const float4 wv = *(const float4*)&W1s[k4 * 4 + kk][tx * 4];
            const float x0 = (&xr0.x)[kk];
            const float x1 = (&xr1.x)[kk];
            const float x2 = (&xr2.x)[kk];
            const float x3 = (&xr3.x)[kk];
            acc[0][0] += x0 * wv.x; acc[0][1] += x0 * wv.y;
            acc[0][2] += x0 * wv.z; acc[0][3] += x0 * wv.w;
            acc[1][0] += x1 * wv.x; acc[1][1] += x1 * wv.y;
            acc[1][2] += x1 * wv.z; acc[1][3] += x1 * wv.w;
            acc[2][0] += x2 * wv.x; acc[2][1] += x2 * wv.y;
            acc[2][2] += x2 * wv.z; acc[2][3] += x2 * wv.w;
            acc[3][0] += x3 * wv.x; acc[3][1] += x3 * wv.y;
            acc[3][2] += x3 * wv.z; acc[3][3] += x3 * wv.w;
        }
    }

    const float4 bv = *(const float4*)&b1[tx * 4];
    __syncthreads();   // done reading Xs as X
#pragma unroll
    for (int i = 0; i < 4; ++i) {
        Xs[ty * 4 + i][tx * 4 + 0] = fmaxf(acc[i][0] + bv.x, 0.f);
        Xs[ty * 4 + i][tx * 4 + 1] = fmaxf(acc[i][1] + bv.y, 0.f);
        Xs[ty * 4 + i][tx * 4 + 2] = fmaxf(acc[i][2] + bv.z, 0.f);
        Xs[ty * 4 + i][tx * 4 + 3] = fmaxf(acc[i][3] + bv.w, 0.f);
    }
    __syncthreads();

    float a2[4][2] = {{0,0},{0,0},{0,0},{0,0}};
#pragma unroll 8
    for (int k = 0; k < 64; ++k) {
        const float2 wv = *(const float2*)&W2s[k][tx * 2];
        const float t0 = Xs[ty * 4 + 0][k];
        const float t1 = Xs[ty * 4 + 1][k];
        const float t2 = Xs[ty * 4 + 2][k];
        const float t3 = Xs[ty * 4 + 3][k];
        a2[0][0] += t0 * wv.x; a2[0][1] += t0 * wv.y;
        a2[1][0] += t1 * wv.x; a2[1][1] += t1 * wv.y;
        a2[2][0] += t2 * wv.x; a2[2][1] += t2 * wv.y;
        a2[3][0] += t3 * wv.x; a2[3][1] += t3 * wv.y;
    }
    const float2 b2v = *(const float2*)&b2[tx * 2];
#pragma unroll
    for (int i = 0; i < 4; ++i) {
        const int r = row0 + ty * 4 + i;
        if (r < N) {
            float2 o;
            o.x = a2[i][0] + b2v.x;
            o.y = a2[i][1] + b2v.y;
            *(float2*)&out[(size_t)r * 32 + tx * 2] = o;
        }
    }
}

// ===========================================================================
// CSR build: coarse partition -> in-bucket scatter (hist fused into gemm1)
// ===========================================================================
#define PC_EPT 8
#define PC_TILE 2048
__global__ __launch_bounds__(256) void partition_coarse(
    const int* __restrict__ ei, int E, const int* __restrict__ bhist,
    int* __restrict__ gcurs, int* __restrict__ pairs)
{
    __shared__ int sc[NBUCK];
    __shared__ int hist[NBUCK];
    __shared__ int base[NBUCK];
    const int t = threadIdx.x;

    const int bh = bhist[t];
    sc[t] = bh; __syncthreads();
    for (int off = 1; off < 256; off <<= 1) {
        int v = sc[t];
        if (t >= off) v += sc[t - off];
        __syncthreads(); sc[t] = v; __syncthreads();
    }
    const int bbase = sc[t] - bh;
    hist[t] = 0;
    __syncthreads();

    const int tile0 = blockIdx.x * PC_TILE;
    int sv[PC_EPT], dv[PC_EPT], rk[PC_EPT];
#pragma unroll
    for (int i = 0; i < PC_EPT; ++i) {
        const int e = tile0 + i * 256 + t;
        if (e < E) {
            sv[i] = ei[e];
            dv[i] = ei[E + e];
            rk[i] = atomicAdd(&hist[dv[i] >> 8], 1);
        } else dv[i] = -1;
    }
    __syncthreads();
    if (hist[t] > 0) base[t] = bbase + atomicAdd(&gcurs[t], hist[t]);
    __syncthreads();
#pragma unroll
    for (int i = 0; i < PC_EPT; ++i) {
        if (dv[i] >= 0) {
            const int b = dv[i] >> 8;
            pairs[base[b] + rk[i]] = sv[i] | ((dv[i] & 255) << 16);
        }
    }
}

__global__ __launch_bounds__(256) void fine_scatter(
    const int* __restrict__ bhist, const int* __restrict__ pairs,
    int N, int E, int* __restrict__ row_off, int* __restrict__ csr_src)
{
    __shared__ int sc[NBUCK];
    __shared__ int cnt[NBUCK];
    __shared__ int cur[NBUCK];
    const int t = threadIdx.x, b = blockIdx.x;

    const int bh = bhist[t];
    sc[t] = bh; __syncthreads();
    for (int off = 1; off < 256; off <<= 1) {
        int v = sc[t];
        if (t >= off) v += sc[t - off];
        __syncthreads(); sc[t] = v; __syncthreads();
    }
    sc[t] -= bh;
    cnt[t] = 0;
    __syncthreads();

    const int sb = sc[b];
    const int se = sb + bhist[b];

    for (int p = sb + t; p < se; p += 256)
        atomicAdd(&cnt[pairs[p] >> 16], 1);
    __syncthreads();

    const int c = cnt[t];
    cur[t] = c; __syncthreads();
    for (int off = 1; off < 256; off <<= 1) {
        int v = cur[t];
        if (t >= off) v += cur[t - off];
        __syncthreads(); cur[t] = v; __syncthreads();
    }
    const int node_off = sb + cur[t] - c;
    __syncthreads();
    cur[t] = node_off;
    const int n = b * 256 + t;
    if (n < N) row_off[n] = node_off;
    if (b == gridDim.x - 1 && t == 0) row_off[N] = E;
    __syncthreads();

    for (int p = sb + t; p < se; p += 256) {
        const int v = pairs[p];
        const int pos = atomicAdd(&cur[v >> 16], 1);
        csr_src[pos] = v & 0xFFFF;
    }
}

// ===========================================================================
// GAT aggregation (R8-proven v5): one wave per dst, no-max softmax
// (shift-invariance, |e| << 88). UNROLL x4: 16 edges in flight per wave,
// 256B gathers (16 lanes x 16B per edge group).
// ===========================================================================
__global__ __launch_bounds__(256) void gat_aggregate(
    const int* __restrict__ row_off, const int* __restrict__ csr_src,
    const float* __restrict__ h, const float* __restrict__ as,
    const float* __restrict__ ad, const float* __restrict__ bias,
    float* __restrict__ out, int N)
{
    const int wv = (blockIdx.x * 256 + threadIdx.x) >> 6;
    if (wv >= N) return;
    const int d    = wv;
    const int lane = threadIdx.x & 63;
    const int g    = lane >> 4;
    const int gl   = lane & 15;

    const int beg = row_off[d], end = row_off[d + 1];
    const float add = ad[d];

    float  den  = 0.f;
    float4 acc0 = {0.f,0.f,0.f,0.f}, acc1 = {0.f,0.f,0.f,0.f};
    float4 acc2 = {0.f,0.f,0.f,0.f}, acc3 = {0.f,0.f,0.f,0.f};

    // prefetch src indices one 16-edge super-chunk ahead
    int s0 = (beg      + g < end) ? csr_src[beg      + g] : 0;
    int s1 = (beg +  4 + g < end) ? csr_src[beg +  4 + g] : 0;
    int s2 = (beg +  8 + g < end) ? csr_src[beg +  8 + g] : 0;
    int s3 = (beg + 12 + g < end) ? csr_src[beg + 12 + g] : 0;

    for (int e0 = beg; e0 < end; e0 += 16) {
        const bool v0 = (e0      + g < end);
        const bool v1 = (e0 +  4 + g < end);
        const bool v2 = (e0 +  8 + g < end);
        const bool v3 = (e0 + 12 + g < end);
        const int cs0 = s0, cs1 = s1, cs2 = s2, cs3 = s3;

        s0 = (e0 + 16 + g < end) ? csr_src[e0 + 16 + g] : 0;
        s1 = (e0 + 20 + g < end) ? csr_src[e0 + 20 + g] : 0;
        s2 = (e0 + 24 + g < end) ? csr_src[e0 + 24 + g] : 0;
        s3 = (e0 + 28 + g < end) ? csr_src[e0 + 28 + g] : 0;

        // 4 independent gathers + 4 alpha loads issued up front
        const float4 h0 = *(const float4*)&h[(size_t)cs0 * 64 + gl * 4];
        const float4 h1 = *(const float4*)&h[(size_t)cs1 * 64 + gl * 4];
        const float4 h2 = *(const float4*)&h[(size_t)cs2 * 64 + gl * 4];
        const float4 h3 = *(const float4*)&h[(size_t)cs3 * 64 + gl * 4];
        const float  a0 = as[cs0];
        const float  a1 = as[cs1];
        const float  a2 = as[cs2];
        const float  a3 = as[cs3];

        float e0v = a0 + add; e0v = (e0v >= 0.f) ? e0v : NEG_SLOPE * e0v;
        float e1v = a1 + add; e1v = (e1v >= 0.f) ? e1v : NEG_SLOPE * e1v;
        float e2v = a2 + add; e2v = (e2v >= 0.f) ? e2v : NEG_SLOPE * e2v;
        float e3v = a3 + add; e3v = (e3v >= 0.f) ? e3v : NEG_SLOPE * e3v;

        const float w0 = v0 ? __expf(e0v) : 0.f;
        const float w1 = v1 ? __expf(e1v) : 0.f;
        const float w2 = v2 ? __expf(e2v) : 0.f;
        const float w3 = v3 ? __expf(e3v) : 0.f;

        den += (w0 + w1) + (w2 + w3);
        acc0.x += w0 * h0.x; acc0.y += w0 * h0.y;
        acc0.z += w0 * h0.z; acc0.w += w0 * h0.w;
        acc1.x += w1 * h1.x; acc1.y += w1 * h1.y;
        acc1.z += w1 * h1.z; acc1.w += w1 * h1.w;
        acc2.x += w2 * h2.x; acc2.y += w2 * h2.y;
        acc2.z += w2 * h2.z; acc2.w += w2 * h2.w;
        acc3.x += w3 * h3.x; acc3.y += w3 * h3.y;
        acc3.z += w3 * h3.z; acc3.w += w3 * h3.w;
    }

    float4 acc;
    acc.x = (acc0.x + acc1.x) + (acc2.x + acc3.x);
    acc.y = (acc0.y + acc1.y) + (acc2.y + acc3.y);
    acc.z = (acc0.z + acc1.z) + (acc2.z + acc3.z);
    acc.w = (acc0.w + acc1.w) + (acc2.w + acc3.w);

    // reduce the 4 edge-groups (lanes differ in bits 4,5)
#pragma unroll
    for (int off = 16; off <= 32; off <<= 1) {
        acc.x += __shfl_xor(acc.x, off, 64);
        acc.y += __shfl_xor(acc.y, off, 64);
        acc.z += __shfl_xor(acc.z, off, 64);
        acc.w += __shfl_xor(acc.w, off, 64);
        den   += __shfl_xor(den,   off, 64);
    }

    if (g == 0) {
        const float4 bvv = *(const float4*)&bias[gl * 4];
        const float inv = (den > 0.f) ? (1.f / den) : 0.f;
        float4 o;
        o.x = fmaxf(acc.x * inv + bvv.x, 0.f);
        o.y = fmaxf(acc.y * inv + bvv.y, 0.f);
        o.z = fmaxf(acc.z * inv + bvv.z, 0.f);
        o.w = fmaxf(acc.w * inv + bvv.w, 0.f);
        *(float4*)&out[(size_t)d * 64 + gl * 4] = o;
    }
}

extern "C" void kernel_launch(void* const* d_in, const int* in_sizes, int n_in,
                              void* d_out, int out_size, void* d_ws, size_t ws_size,
                              hipStream_t stream)
{
    const float* x  = (const float*)d_in[0];
    const int*   ei = (const int*)d_in[1];
    const float* W[3]    = {(const float*)d_in[2], (const float*)d_in[6],  (const float*)d_in[10]};
    const float* asrc[3] = {(const float*)d_in[3], (const float*)d_in[7],  (const float*)d_in[11]};
    const float* adst[3] = {(const float*)d_in[4], (const float*)d_in[8],  (const float*)d_in[12]};
    const float* bia[3]  = {(const float*)d_in[5], (const float*)d_in[9],  (const float*)d_in[13]};
    const float* lin1W = (const float*)d_in[14];
    const float* lin1b = (const float*)d_in[15];
    const float* lin2W = (const float*)d_in[16];
    const float* lin2b = (const float*)d_in[17];

    const int N = in_sizes[0] / 64;
    const int E = in_sizes[1] / 2;
    const int B = (N + 255) / 256;            // coarse buckets (<=256)

    // workspace layout
    float* X       = (float*)d_ws;            // N*64
    float* H       = X + (size_t)N * 64;      // N*64
    float* AS      = H + (size_t)N * 64;      // N
    float* AD      = AS + N;                  // N
    int*   row_off = (int*)(AD + N);          // N+1
    int*   csr_src = row_off + (N + 1);       // E
    int*   bhist   = csr_src + E;             // 256
    int*   gcurs   = bhist + 256;             // 256
    int*   pairs   = gcurs + 256;             // E

    const int g64_grid = (N + 63) / 64;
    const int agg_grid = (N + 3) / 4;
    const int pc_grid  = (E + PC_TILE - 1) / PC_TILE;

    hipMemsetAsync(bhist, 0, 512 * sizeof(int), stream);

    // ---- layer 1 GEMM (+ fused bucket histogram) ----
    gemm64<true, true><<<g64_grid, 256, 0, stream>>>(
        x, W[0], asrc[0], adst[0], H, AS, AD, N, ei, E, bhist);

    // ---- CSR build ----
    partition_coarse<<<pc_grid, 256, 0, stream>>>(ei, E, bhist, gcurs, pairs);
    fine_scatter<<<B, 256, 0, stream>>>(bhist, pairs, N, E, row_off, csr_src);

    // ---- layer 1 aggregate ----
    gat_aggregate<<<agg_grid, 256, 0, stream>>>(
        row_off, csr_src, H, AS, AD, bia[0], X, N);

    // ---- layers 2,3 ----
    for (int l = 1; l < 3; ++l) {
        gemm64<true, false><<<g64_grid, 256, 0, stream>>>(
            X, W[l], asrc[l], adst[l], H, AS, AD, N, nullptr, 0, nullptr);
        gat_aggregate<<<agg_grid, 256, 0, stream>>>(
            row_off, csr_src, H, AS, AD, bia[l], X, N);
    }

    // ---- fused MLP head ----
    gemm_head<<<g64_grid, 256, 0, stream>>>(
        X, lin1W, lin1b, lin2W, lin2b, (float*)d_out, N);
}

// Round 11
// 229.840 us; speedup vs baseline: 1.3672x; 1.0817x over previous
//
#include <hip/hip_runtime.h>

#define NEG_SLOPE 0.2f
#define NBUCK 256

// ---------------------------------------------------------------------------
// Device helper: R8-proven GAT aggregation for one block's 64 dst rows,
// results written to Xs LDS tile (bias + relu applied).
// Wave w handles rows row0 + w*16 .. +15, one node at a time.
// No-max softmax (shift-invariance, |e| << 88). 16 gathers in flight.
// ---------------------------------------------------------------------------
__device__ __forceinline__ void agg_into_lds(
    const int* __restrict__ row_off, const int* __restrict__ csr_src,
    const float* __restrict__ h, const float* __restrict__ as,
    const float* __restrict__ ad, const float* __restrict__ bias,
    float (*Xs)[68], int N, int row0)
{
    const int lane = threadIdx.x & 63;
    const int wave = threadIdx.x >> 6;        // 0..3
    const int g    = lane >> 4;               // edge group 0..3
    const int gl   = lane & 15;               // col group: 4*gl..4*gl+3

    const float4 bvv = *(const float4*)&bias[gl * 4];

    for (int it = 0; it < 16; ++it) {
        const int dl = wave * 16 + it;
        const int d  = row0 + dl;
        if (d >= N) break;

        const int beg = row_off[d], end = row_off[d + 1];
        const float add = ad[d];

        float  den  = 0.f;
        float4 acc0 = {0.f,0.f,0.f,0.f}, acc1 = {0.f,0.f,0.f,0.f};
        float4 acc2 = {0.f,0.f,0.f,0.f}, acc3 = {0.f,0.f,0.f,0.f};

        int s0 = (beg      + g < end) ? csr_src[beg      + g] : 0;
        int s1 = (beg +  4 + g < end) ? csr_src[beg +  4 + g] : 0;
        int s2 = (beg +  8 + g < end) ? csr_src[beg +  8 + g] : 0;
        int s3 = (beg + 12 + g < end) ? csr_src[beg + 12 + g] : 0;

        for (int e0 = beg; e0 < end; e0 += 16) {
            const bool v0 = (e0      + g < end);
            const bool v1 = (e0 +  4 + g < end);
            const bool v2 = (e0 +  8 + g < end);
            const bool v3 = (e0 + 12 + g < end);
            const int cs0 = s0, cs1 = s1, cs2 = s2, cs3 = s3;

            s0 = (e0 + 16 + g < end) ? csr_src[e0 + 16 + g] : 0;
            s1 = (e0 + 20 + g < end) ? csr_src[e0 + 20 + g] : 0;
            s2 = (e0 + 24 + g < end) ? csr_src[e0 + 24 + g] : 0;
            s3 = (e0 + 28 + g < end) ? csr_src[e0 + 28 + g] : 0;

            const float4 h0 = *(const float4*)&h[(size_t)cs0 * 64 + gl * 4];
            const float4 h1 = *(const float4*)&h[(size_t)cs1 * 64 + gl * 4];
            const float4 h2 = *(const float4*)&h[(size_t)cs2 * 64 + gl * 4];
            const float4 h3 = *(const float4*)&h[(size_t)cs3 * 64 + gl * 4];
            const float  a0 = as[cs0];
            const float  a1 = as[cs1];
            const float  a2 = as[cs2];
            const float  a3 = as[cs3];

            float e0v = a0 + add; e0v = (e0v >= 0.f) ? e0v : NEG_SLOPE * e0v;
            float e1v = a1 + add; e1v = (e1v >= 0.f) ? e1v : NEG_SLOPE * e1v;
            float e2v = a2 + add; e2v = (e2v >= 0.f) ? e2v : NEG_SLOPE * e2v;
            float e3v = a3 + add; e3v = (e3v >= 0.f) ? e3v : NEG_SLOPE * e3v;

            const float w0 = v0 ? __expf(e0v) : 0.f;
            const float w1 = v1 ? __expf(e1v) : 0.f;
            const float w2 = v2 ? __expf(e2v) : 0.f;
            const float w3 = v3 ? __expf(e3v) : 0.f;

            den += (w0 + w1) + (w2 + w3);
            acc0.x += w0 * h0.x; acc0.y += w0 * h0.y;
            acc0.z += w0 * h0.z; acc0.w += w0 * h0.w;
            acc1.x += w1 * h1.x; acc1.y += w1 * h1.y;
            acc1.z += w1 * h1.z; acc1.w += w1 * h1.w;
            acc2.x += w2 * h2.x; acc2.y += w2 * h2.y;
            acc2.z += w2 * h2.z; acc2.w += w2 * h2.w;
            acc3.x += w3 * h3.x; acc3.y += w3 * h3.y;
            acc3.z += w3 * h3.z; acc3.w += w3 * h3.w;
        }

        float4 acc;
        acc.x = (acc0.x + acc1.x) + (acc2.x + acc3.x);
        acc.y = (acc0.y + acc1.y) + (acc2.y + acc3.y);
        acc.z = (acc0.z + acc1.z) + (acc2.z + acc3.z);
        acc.w = (acc0.w + acc1.w) + (acc2.w + acc3.w);

#pragma unroll
        for (int off = 16; off <= 32; off <<= 1) {
            acc.x += __shfl_xor(acc.x, off, 64);
            acc.y += __shfl_xor(acc.y, off, 64);
            acc.z += __shfl_xor(acc.z, off, 64);
            acc.w += __shfl_xor(acc.w, off, 64);
            den   += __shfl_xor(den,   off, 64);
        }

        if (g == 0) {
            const float inv = (den > 0.f) ? (1.f / den) : 0.f;
            Xs[dl][gl * 4 + 0] = fmaxf(acc.x * inv + bvv.x, 0.f);
            Xs[dl][gl * 4 + 1] = fmaxf(acc.y * inv + bvv.y, 0.f);
            Xs[dl][gl * 4 + 2] = fmaxf(acc.z * inv + bvv.z, 0.f);
            Xs[dl][gl * 4 + 3] = fmaxf(acc.w * inv + bvv.w, 0.f);
        }
    }
}

// ===========================================================================
// Layer-1 GEMM: H = x @ W, + alphas; blocks 0..255 also histogram dst>>8.
// (R8-proven scalar-Xs inner loop, VGPR-friendly.)
// ===========================================================================
__global__ __launch_bounds__(256) void gemm64_l1(
    const float* __restrict__ x, const float* __restrict__ W,
    const float* __restrict__ a_src, const float* __restrict__ a_dst,
    float* __restrict__ out, float* __restrict__ alpha_s,
    float* __restrict__ alpha_d, int N,
    const int* __restrict__ ei, int E, int* __restrict__ bhist)
{
    __shared__ float Xs[64][68];
    __shared__ float Ws[64][64];
    __shared__ int   hsh[NBUCK];

    const int row0 = blockIdx.x * 64;

    for (int i = threadIdx.x; i < 1024; i += 256)
        ((float4*)Ws)[i] = ((const float4*)W)[i];
    for (int i = threadIdx.x; i < 1024; i += 256) {
        int r = i >> 4, c4 = (i & 15) * 4;
        float4 v = {0.f, 0.f, 0.f, 0.f};
        if (row0 + r < N) v = *(const float4*)&x[(size_t)(row0 + r) * 64 + c4];
        *(float4*)&Xs[r][c4] = v;
    }
    if (blockIdx.x < 256) hsh[threadIdx.x] = 0;
    __syncthreads();

    const int tx = threadIdx.x & 15;
    const int ty = threadIdx.x >> 4;

    float acc[4][4] = {{0.f,0.f,0.f,0.f},{0.f,0.f,0.f,0.f},
                       {0.f,0.f,0.f,0.f},{0.f,0.f,0.f,0.f}};
#pragma unroll 8
    for (int k = 0; k < 64; ++k) {
        const float4 wv = *(const float4*)&Ws[k][tx * 4];
        const float x0 = Xs[ty * 4 + 0][k];
        const float x1 = Xs[ty * 4 + 1][k];
        const float x2 = Xs[ty * 4 + 2][k];
        const float x3 = Xs[ty * 4 + 3][k];
        acc[0][0] += x0 * wv.x; acc[0][1] += x0 * wv.y;
        acc[0][2] += x0 * wv.z; acc[0][3] += x0 * wv.w;
        acc[1][0] += x1 * wv.x; acc[1][1] += x1 * wv.y;
        acc[1][2] += x1 * wv.z; acc[1][3] += x1 * wv.w;
        acc[2][0] += x2 * wv.x; acc[2][1] += x2 * wv.y;
        acc[2][2] += x2 * wv.z; acc[2][3] += x2 * wv.w;
        acc[3][0] += x3 * wv.x; acc[3][1] += x3 * wv.y;
        acc[3][2] += x3 * wv.z; acc[3][3] += x3 * wv.w;
    }

#pragma unroll
    for (int i = 0; i < 4; ++i) {
        const int r = row0 + ty * 4 + i;
        if (r < N) {
            float4 o = {acc[i][0], acc[i][1], acc[i][2], acc[i][3]};
            *(float4*)&out[(size_t)r * 64 + tx * 4] = o;
        }
    }

    const float4 asv = *(const float4*)&a_src[tx * 4];
    const float4 adv = *(const float4*)&a_dst[tx * 4];
#pragma unroll
    for (int i = 0; i < 4; ++i) {
        float s = acc[i][0]*asv.x + acc[i][1]*asv.y
                + acc[i][2]*asv.z + acc[i][3]*asv.w;
        float d = acc[i][0]*adv.x + acc[i][1]*adv.y
                + acc[i][2]*adv.z + acc[i][3]*adv.w;
#pragma unroll
        for (int off = 1; off < 16; off <<= 1) {
            s += __shfl_xor(s, off, 16);
            d += __shfl_xor(d, off, 16);
        }
        const int r = row0 + ty * 4 + i;
        if (tx == 0 && r < N) { alpha_s[r] = s; alpha_d[r] = d; }
    }

    if (blockIdx.x < 256) {
        __syncthreads();
        for (int e = blockIdx.x * 256 + threadIdx.x; e < E; e += 256 * 256)
            atomicAdd(&hsh[((unsigned)ei[E + e]) >> 8], 1);
        __syncthreads();
        if (hsh[threadIdx.x]) atomicAdd(&bhist[threadIdx.x], hsh[threadIdx.x]);
    }
}

// ===========================================================================
// Fused agg(l) + gemm(l+1): agg 64 dst rows into Xs LDS, then H_out = Xs@W.
// Eliminates the X global round trip.
// ===========================================================================
__global__ __launch_bounds__(256) void agg_gemm(
    const int* __restrict__ row_off, const int* __restrict__ csr_src,
    const float* __restrict__ h_in, const float* __restrict__ as_in,
    const float* __restrict__ ad_in, const float* __restrict__ bias,
    const float* __restrict__ W, const float* __restrict__ a_src,
    const float* __restrict__ a_dst, float* __restrict__ h_out,
    float* __restrict__ alpha_s, float* __restrict__ alpha_d, int N)
{
    __shared__ float Xs[64][68];
    __shared__ float Ws[64][64];

    const int row0 = blockIdx.x * 64;

    for (int i = threadIdx.x; i < 1024; i += 256)
        ((float4*)Ws)[i] = ((const float4*)W)[i];

    agg_into_lds(row_off, csr_src, h_in, as_in, ad_in, bias, Xs, N, row0);
    __syncthreads();

    const int tx = threadIdx.x & 15;
    const int ty = threadIdx.x >> 4;

    float acc[4][4] = {{0.f,0.f,0.f,0.f},{0.f,0.f,0.f,0.f},
                       {0.f,0.f,0.f,0.f},{0.f,0.f,0.f,0.f}};
#pragma unroll 8
    for (int k = 0; k < 64; ++k) {
        const float4 wv = *(const float4*)&Ws[k][tx * 4];
        const float x0 = Xs[ty * 4 + 0][k];
        const float x1 = Xs[ty * 4 + 1][k];
        const float x2 = Xs[ty * 4 + 2][k];
        const float x3 = Xs[ty * 4 + 3][k];
        acc[0][0] += x0 * wv.x; acc[0][1] += x0 * wv.y;
        acc[0][2] += x0 * wv.z; acc[0][3] += x0 * wv.w;
        acc[1][0] += x1 * wv.x; acc[1][1] += x1 * wv.y;
        acc[1][2] += x1 * wv.z; acc[1][3] += x1 * wv.w;
        acc[2][0] += x2 * wv.x; acc[2][1] += x2 * wv.y;
        acc[2][2] += x2 * wv.z; acc[2][3] += x2 * wv.w;
        acc[3][0] += x3 * wv.x; acc[3][1] += x3 * wv.y;
        acc[3][2] += x3 * wv.z; acc[3][3] += x3 * wv.w;
    }

#pragma unroll
    for (int i = 0; i < 4; ++i) {
        const int r = row0 + ty * 4 + i;
        if (r < N) {
            float4 o = {acc[i][0], acc[i][1], acc[i][2], acc[i][3]};
            *(float4*)&h_out[(size_t)r * 64 + tx * 4] = o;
        }
    }

    const float4 asv = *(const float4*)&a_src[tx * 4];
    const float4 adv = *(const float4*)&a_dst[tx * 4];
#pragma unroll
    for (int i = 0; i < 4; ++i) {
        float s = acc[i][0]*asv.x + acc[i][1]*asv.y
                + acc[i][2]*asv.z + acc[i][3]*asv.w;
        float d = acc[i][0]*adv.x + acc[i][1]*adv.y
                + acc[i][2]*adv.z + acc[i][3]*adv.w;
#pragma unroll
        for (int off = 1; off < 16; off <<= 1) {
            s += __shfl_xor(s, off, 16);
            d += __shfl_xor(d, off, 16);
        }
        const int r = row0 + ty * 4 + i;
        if (tx == 0 && r < N) { alpha_s[r] = s; alpha_d[r] = d; }
    }
}

// ===========================================================================
// Fused agg(3) + MLP head: agg into Xs, T = relu(Xs@W1+b1) in Xs,
// out = T@W2 + b2.
// ===========================================================================
__global__ __launch_bounds__(256) void agg_head(
    const int* __restrict__ row_off, const int* __restrict__ csr_src,
    const float* __restrict__ h_in, const float* __restrict__ as_in,
    const float* __restrict__ ad_in, const float* __restrict__ bias,
    const float* __restrict__ W1, const float* __restrict__ b1,
    const float* __restrict__ W2, const float* __restrict__ b2,
    float* __restrict__ out, int N)
{
    __shared__ float Xs[64][68];
    __shared__ float W1s[64][64];
    __shared__ float W2s[64][32];

    const int row0 = blockIdx.x * 64;

    for (int i = threadIdx.x; i < 1024; i += 256)
        ((float4*)W1s)[i] = ((const float4*)W1)[i];
    for (int i = threadIdx.x; i < 512; i += 256)
        ((float4*)W2s)[i] = ((const float4*)W2)[i];

    agg_into_lds(row_off, csr_src, h_in, as_in, ad_in, bias, Xs, N, row0);
    __syncthreads();

    const int tx = threadIdx.x & 15;
    const int ty = threadIdx.x >> 4;

    float acc[4][4] = {{0,0,0,0},{0,0,0,0},{0,0,0,0},{0,0,0,0}};
#pragma unroll 8
    for (int k = 0; k < 64; ++k) {
        const float4 wv = *(const float4*)&W1s[k][tx * 4];
        const float x0 = Xs[ty * 4 + 0][k];
        const float x1 = Xs[ty * 4 + 1][k];
        const float x2 = Xs[ty * 4 + 2][k];
        const float x3 = Xs[ty * 4 + 3][k];
        acc[0][0] += x0 * wv.x; acc[0][1] += x0 * wv.y;
        acc[0][2] += x0 * wv.z; acc[0][3] += x0 * wv.w;
        acc[1][0] += x1 * wv.x; acc[1][1] += x1 * wv.y;
        acc[1][2] += x1 * wv.z; acc[1][3] += x1 * wv.w;
        acc[2][0] += x2 * wv.x; acc[2][1] += x2 * wv.y;
        acc[2][2] += x2 * wv.z; acc[2][3] += x2 * wv.w;
        acc[3][0] += x3 * wv.x; acc[3][1] += x3 * wv.y;
        acc[3][2] += x3 * wv.z; acc[3][3] += x3 * wv.w;
    }

    const float4 bv = *(const float4*)&b1[tx * 4];
    __syncthreads();   // done reading Xs as agg output
#pragma unroll
    for (int i = 0; i < 4; ++i) {
        Xs[ty * 4 + i][tx * 4 + 0] = fmaxf(acc[i][0] + bv.x, 0.f);
        Xs[ty * 4 + i][tx * 4 + 1] = fmaxf(acc[i][1] + bv.y, 0.f);
        Xs[ty * 4 + i][tx * 4 + 2] = fmaxf(acc[i][2] + bv.z, 0.f);
        Xs[ty * 4 + i][tx * 4 + 3] = fmaxf(acc[i][3] + bv.w, 0.f);
    }
    __syncthreads();

    float a2[4][2] = {{0,0},{0,0},{0,0},{0,0}};
#pragma unroll 8
    for (int k = 0; k < 64; ++k) {
        const float2 wv = *(const float2*)&W2s[k][tx * 2];
        const float t0 = Xs[ty * 4 + 0][k];
        const float t1 = Xs[ty * 4 + 1][k];
        const float t2 = Xs[ty * 4 + 2][k];
        const float t3 = Xs[ty * 4 + 3][k];
        a2[0][0] += t0 * wv.x; a2[0][1] += t0 * wv.y;
        a2[1][0] += t1 * wv.x; a2[1][1] += t1 * wv.y;
        a2[2][0] += t2 * wv.x; a2[2][1] += t2 * wv.y;
        a2[3][0] += t3 * wv.x; a2[3][1] += t3 * wv.y;
    }
    const float2 b2v = *(const float2*)&b2[tx * 2];
#pragma unroll
    for (int i = 0; i < 4; ++i) {
        const int r = row0 + ty * 4 + i;
        if (r < N) {
            float2 o = {a2[i][0] + b2v.x, a2[i][1] + b2v.y};
            *(float2*)&out[(size_t)r * 32 + tx * 2] = o;
        }
    }
}

// ===========================================================================
// CSR build: coarse partition -> in-bucket scatter (hist fused into gemm1)
// ===========================================================================
#define PC_EPT 8
#define PC_TILE 2048
__global__ __launch_bounds__(256) void partition_coarse(
    const int* __restrict__ ei, int E, const int* __restrict__ bhist,
    int* __restrict__ gcurs, int* __restrict__ pairs)
{
    __shared__ int sc[NBUCK];
    __shared__ int hist[NBUCK];
    __shared__ int base[NBUCK];
    const int t = threadIdx.x;

    const int bh = bhist[t];
    sc[t] = bh; __syncthreads();
    for (int off = 1; off < 256; off <<= 1) {
        int v = sc[t];
        if (t >= off) v += sc[t - off];
        __syncthreads(); sc[t] = v; __syncthreads();
    }
    const int bbase = sc[t] - bh;
    hist[t] = 0;
    __syncthreads();

    const int tile0 = blockIdx.x * PC_TILE;
    int sv[PC_EPT], dv[PC_EPT], rk[PC_EPT];
#pragma unroll
    for (int i = 0; i < PC_EPT; ++i) {
        const int e = tile0 + i * 256 + t;
        if (e < E) {
            sv[i] = ei[e];
            dv[i] = ei[E + e];
            rk[i] = atomicAdd(&hist[dv[i] >> 8], 1);
        } else dv[i] = -1;
    }
    __syncthreads();
    if (hist[t] > 0) base[t] = bbase + atomicAdd(&gcurs[t], hist[t]);
    __syncthreads();
#pragma unroll
    for (int i = 0; i < PC_EPT; ++i) {
        if (dv[i] >= 0) {
            const int b = dv[i] >> 8;
            pairs[base[b] + rk[i]] = sv[i] | ((dv[i] & 255) << 16);
        }
    }
}

__global__ __launch_bounds__(256) void fine_scatter(
    const int* __restrict__ bhist, const int* __restrict__ pairs,
    int N, int E, int* __restrict__ row_off, int* __restrict__ csr_src)
{
    __shared__ int sc[NBUCK];
    __shared__ int cnt[NBUCK];
    __shared__ int cur[NBUCK];
    const int t = threadIdx.x, b = blockIdx.x;

    const int bh = bhist[t];
    sc[t] = bh; __syncthreads();
    for (int off = 1; off < 256; off <<= 1) {
        int v = sc[t];
        if (t >= off) v += sc[t - off];
        __syncthreads(); sc[t] = v; __syncthreads();
    }
    sc[t] -= bh;
    cnt[t] = 0;
    __syncthreads();

    const int sb = sc[b];
    const int se = sb + bhist[b];

    for (int p = sb + t; p < se; p += 256)
        atomicAdd(&cnt[pairs[p] >> 16], 1);
    __syncthreads();

    const int c = cnt[t];
    cur[t] = c; __syncthreads();
    for (int off = 1; off < 256; off <<= 1) {
        int v = cur[t];
        if (t >= off) v += cur[t - off];
        __syncthreads(); cur[t] = v; __syncthreads();
    }
    const int node_off = sb + cur[t] - c;
    __syncthreads();
    cur[t] = node_off;
    const int n = b * 256 + t;
    if (n < N) row_off[n] = node_off;
    if (b == gridDim.x - 1 && t == 0) row_off[N] = E;
    __syncthreads();

    for (int p = sb + t; p < se; p += 256) {
        const int v = pairs[p];
        const int pos = atomicAdd(&cur[v >> 16], 1);
        csr_src[pos] = v & 0xFFFF;
    }
}

extern "C" void kernel_launch(void* const* d_in, const int* in_sizes, int n_in,
                              void* d_out, int out_size, void* d_ws, size_t ws_size,
                              hipStream_t stream)
{
    const float* x  = (const float*)d_in[0];
    const int*   ei = (const int*)d_in[1];
    const float* W[3]    = {(const float*)d_in[2], (const float*)d_in[6],  (const float*)d_in[10]};
    const float* asrc[3] = {(const float*)d_in[3], (const float*)d_in[7],  (const float*)d_in[11]};
    const float* adst[3] = {(const float*)d_in[4], (const float*)d_in[8],  (const float*)d_in[12]};
    const float* bia[3]  = {(const float*)d_in[5], (const float*)d_in[9],  (const float*)d_in[13]};
    const float* lin1W = (const float*)d_in[14];
    const float* lin1b = (const float*)d_in[15];
    const float* lin2W = (const float*)d_in[16];
    const float* lin2b = (const float*)d_in[17];

    const int N = in_sizes[0] / 64;
    const int E = in_sizes[1] / 2;
    const int B = (N + 255) / 256;            // coarse buckets (<=256)

    // workspace layout (double-buffered H and alphas; no X buffer)
    float* Ha      = (float*)d_ws;            // N*64
    float* Hb      = Ha + (size_t)N * 64;     // N*64
    float* ASa     = Hb + (size_t)N * 64;     // N
    float* ADa     = ASa + N;                 // N
    float* ASb     = ADa + N;                 // N
    float* ADb     = ASb + N;                 // N
    int*   row_off = (int*)(ADb + N);         // N+1
    int*   csr_src = row_off + (N + 1);       // E
    int*   bhist   = csr_src + E;             // 256
    int*   gcurs   = bhist + 256;             // 256
    int*   pairs   = gcurs + 256;             // E

    const int g64_grid = (N + 63) / 64;
    const int pc_grid  = (E + PC_TILE - 1) / PC_TILE;

    hipMemsetAsync(bhist, 0, 512 * sizeof(int), stream);

    // layer-1 GEMM (+ fused bucket histogram)
    gemm64_l1<<<g64_grid, 256, 0, stream>>>(
        x, W[0], asrc[0], adst[0], Ha, ASa, ADa, N, ei, E, bhist);

    // CSR build
    partition_coarse<<<pc_grid, 256, 0, stream>>>(ei, E, bhist, gcurs, pairs);
    fine_scatter<<<B, 256, 0, stream>>>(bhist, pairs, N, E, row_off, csr_src);

    // agg(1) + gemm(2):  Ha/ASa/ADa -> Hb/ASb/ADb
    agg_gemm<<<g64_grid, 256, 0, stream>>>(
        row_off, csr_src, Ha, ASa, ADa, bia[0],
        W[1], asrc[1], adst[1], Hb, ASb, ADb, N);

    // agg(2) + gemm(3):  Hb/ASb/ADb -> Ha/ASa/ADa
    agg_gemm<<<g64_grid, 256, 0, stream>>>(
        row_off, csr_src, Hb, ASb, ADb, bia[1],
        W[2], asrc[2], adst[2], Ha, ASa, ADa, N);

    // agg(3) + MLP head
    agg_head<<<g64_grid, 256, 0, stream>>>(
        row_off, csr_src, Ha, ASa, ADa, bia[2],
        lin1W, lin1b, lin2W, lin2b, (float*)d_out, N);
}

// Round 12
// 202.510 us; speedup vs baseline: 1.5517x; 1.1350x over previous
//
#include <hip/hip_runtime.h>

#define NEG_SLOPE 0.2f
#define NBUCK 256

// ===========================================================================
// Register-blocked GEMM: out[N,64] = x[N,64] @ W[64,64]
// 64x64 tile per block; 256 threads; 4x4 outputs/thread. Scalar Xs reads
// (VGPR-friendly: ~84 VGPRs, full occupancy — R10's b128 variant hit a
// 252-VGPR occupancy cliff).
// WANT_ALPHA: also alpha_s/alpha_d = (out * a).sum(-1) via 16-lane reduce.
// DO_HIST: blocks 0..255 additionally histogram edge dst>>8 into bhist.
// ===========================================================================
template <bool WANT_ALPHA, bool DO_HIST>
__global__ __launch_bounds__(256) void gemm64(
    const float* __restrict__ x, const float* __restrict__ W,
    const float* __restrict__ a_src, const float* __restrict__ a_dst,
    float* __restrict__ out, float* __restrict__ alpha_s,
    float* __restrict__ alpha_d, int N,
    const int* __restrict__ ei, int E, int* __restrict__ bhist)
{
    __shared__ float Xs[64][68];   // +4 pad: column reads 2-way max (free)
    __shared__ float Ws[64][64];
    __shared__ int   hsh[NBUCK];

    const int row0 = blockIdx.x * 64;

    for (int i = threadIdx.x; i < 1024; i += 256)
        ((float4*)Ws)[i] = ((const float4*)W)[i];
    for (int i = threadIdx.x; i < 1024; i += 256) {
        int r = i >> 4, c4 = (i & 15) * 4;
        float4 v = {0.f, 0.f, 0.f, 0.f};
        if (row0 + r < N) v = *(const float4*)&x[(size_t)(row0 + r) * 64 + c4];
        *(float4*)&Xs[r][c4] = v;
    }
    if (DO_HIST && blockIdx.x < 256) hsh[threadIdx.x] = 0;
    __syncthreads();

    const int tx = threadIdx.x & 15;
    const int ty = threadIdx.x >> 4;

    float acc[4][4] = {{0.f,0.f,0.f,0.f},{0.f,0.f,0.f,0.f},
                       {0.f,0.f,0.f,0.f},{0.f,0.f,0.f,0.f}};

#pragma unroll 8
    for (int k = 0; k < 64; ++k) {
        const float4 wv = *(const float4*)&Ws[k][tx * 4];
        const float x0 = Xs[ty * 4 + 0][k];
        const float x1 = Xs[ty * 4 + 1][k];
        const float x2 = Xs[ty * 4 + 2][k];
        const float x3 = Xs[ty * 4 + 3][k];
        acc[0][0] += x0 * wv.x; acc[0][1] += x0 * wv.y;
        acc[0][2] += x0 * wv.z; acc[0][3] += x0 * wv.w;
        acc[1][0] += x1 * wv.x; acc[1][1] += x1 * wv.y;
        acc[1][2] += x1 * wv.z; acc[1][3] += x1 * wv.w;
        acc[2][0] += x2 * wv.x; acc[2][1] += x2 * wv.y;
        acc[2][2] += x2 * wv.z; acc[2][3] += x2 * wv.w;
        acc[3][0] += x3 * wv.x; acc[3][1] += x3 * wv.y;
        acc[3][2] += x3 * wv.z; acc[3][3] += x3 * wv.w;
    }

#pragma unroll
    for (int i = 0; i < 4; ++i) {
        const int r = row0 + ty * 4 + i;
        if (r < N) {
            float4 o = {acc[i][0], acc[i][1], acc[i][2], acc[i][3]};
            *(float4*)&out[(size_t)r * 64 + tx * 4] = o;
        }
    }

    if (WANT_ALPHA) {
        const float4 asv = *(const float4*)&a_src[tx * 4];
        const float4 adv = *(const float4*)&a_dst[tx * 4];
#pragma unroll
        for (int i = 0; i < 4; ++i) {
            float s = acc[i][0]*asv.x + acc[i][1]*asv.y
                    + acc[i][2]*asv.z + acc[i][3]*asv.w;
            float d = acc[i][0]*adv.x + acc[i][1]*adv.y
                    + acc[i][2]*adv.z + acc[i][3]*adv.w;
#pragma unroll
            for (int off = 1; off < 16; off <<= 1) {
                s += __shfl_xor(s, off, 16);
                d += __shfl_xor(d, off, 16);
            }
            const int r = row0 + ty * 4 + i;
            if (tx == 0 && r < N) { alpha_s[r] = s; alpha_d[r] = d; }
        }
    }

    // fused CSR pass 0: bucket histogram (256 blocks, slice each)
    if (DO_HIST && blockIdx.x < 256) {
        __syncthreads();
        for (int e = blockIdx.x * 256 + threadIdx.x; e < E; e += 256 * 256)
            atomicAdd(&hsh[((unsigned)ei[E + e]) >> 8], 1);
        __syncthreads();
        if (hsh[threadIdx.x]) atomicAdd(&bhist[threadIdx.x], hsh[threadIdx.x]);
    }
}

// ===========================================================================
// Fused MLP head: out[N,32] = relu(X @ W1 + b1) @ W2 + b2
// ===========================================================================
__global__ __launch_bounds__(256) void gemm_head(
    const float* __restrict__ X, const float* __restrict__ W1,
    const float* __restrict__ b1, const float* __restrict__ W2,
    const float* __restrict__ b2, float* __restrict__ out, int N)
{
    __shared__ float Xs[64][68];
    __shared__ float W1s[64][64];
    __shared__ float W2s[64][32];

    const int row0 = blockIdx.x * 64;

    for (int i = threadIdx.x; i < 1024; i += 256)
        ((float4*)W1s)[i] = ((const float4*)W1)[i];
    for (int i = threadIdx.x; i < 512; i += 256)
        ((float4*)W2s)[i] = ((const float4*)W2)[i];
    for (int i = threadIdx.x; i < 1024; i += 256) {
        int r = i >> 4, c4 = (i & 15) * 4;
        float4 v = {0.f, 0.f, 0.f, 0.f};
        if (row0 + r < N) v = *(const float4*)&X[(size_t)(row0 + r) * 64 + c4];
        *(float4*)&Xs[r][c4] = v;
    }
    __syncthreads();

    const int tx = threadIdx.x & 15;
    const int ty = threadIdx.x >> 4;

    float acc[4][4] = {{0,0,0,0},{0,0,0,0},{0,0,0,0},{0,0,0,0}};
#pragma unroll 8
    for (int k = 0; k < 64; ++k) {
        const float4 wv = *(const float4*)&W1s[k][tx * 4];
        const float x0 = Xs[ty * 4 + 0][k];
        const float x1 = Xs[ty * 4 + 1][k];
        const float x2 = Xs[ty * 4 + 2][k];
        const float x3 = Xs[ty * 4 + 3][k];
        acc[0][0] += x0 * wv.x; acc[0][1] += x0 * wv.y;
        acc[0][2] += x0 * wv.z; acc[0][3] += x0 * wv.w;
        acc[1][0] += x1 * wv.x; acc[1][1] += x1 * wv.y;
        acc[1][2] += x1 * wv.z; acc[1][3] += x1 * wv.w;
        acc[2][0] += x2 * wv.x; acc[2][1] += x2 * wv.y;
        acc[2][2] += x2 * wv.z; acc[2][3] += x2 * wv.w;
        acc[3][0] += x3 * wv.x; acc[3][1] += x3 * wv.y;
        acc[3][2] += x3 * wv.z; acc[3][3] += x3 * wv.w;
    }

    const float4 bv = *(const float4*)&b1[tx * 4];
    __syncthreads();   // done reading Xs as X
#pragma unroll
    for (int i = 0; i < 4; ++i) {
        Xs[ty * 4 + i][tx * 4 + 0] = fmaxf(acc[i][0] + bv.x, 0.f);
        Xs[ty * 4 + i][tx * 4 + 1] = fmaxf(acc[i][1] + bv.y, 0.f);
        Xs[ty * 4 + i][tx * 4 + 2] = fmaxf(acc[i][2] + bv.z, 0.f);
        Xs[ty * 4 + i][tx * 4 + 3] = fmaxf(acc[i][3] + bv.w, 0.f);
    }
    __syncthreads();

    float a2[4][2] = {{0,0},{0,0},{0,0},{0,0}};
#pragma unroll 8
    for (int k = 0; k < 64; ++k) {
        const float2 wv = *(const float2*)&W2s[k][tx * 2];
        const float t0 = Xs[ty * 4 + 0][k];
        const float t1 = Xs[ty * 4 + 1][k];
        const float t2 = Xs[ty * 4 + 2][k];
        const float t3 = Xs[ty * 4 + 3][k];
        a2[0][0] += t0 * wv.x; a2[0][1] += t0 * wv.y;
        a2[1][0] += t1 * wv.x; a2[1][1] += t1 * wv.y;
        a2[2][0] += t2 * wv.x; a2[2][1] += t2 * wv.y;
        a2[3][0] += t3 * wv.x; a2[3][1] += t3 * wv.y;
    }
    const float2 b2v = *(const float2*)&b2[tx * 2];
#pragma unroll
    for (int i = 0; i < 4; ++i) {
        const int r = row0 + ty * 4 + i;
        if (r < N) {
            float2 o;
            o.x = a2[i][0] + b2v.x;
            o.y = a2[i][1] + b2v.y;
            *(float2*)&out[(size_t)r * 32 + tx * 2] = o;
        }
    }
}

// ===========================================================================
// CSR build: coarse partition -> in-bucket scatter (hist fused into gemm1)
// ===========================================================================
#define PC_EPT 8
#define PC_TILE 2048
__global__ __launch_bounds__(256) void partition_coarse(
    const int* __restrict__ ei, int E, const int* __restrict__ bhist,
    int* __restrict__ gcurs, int* __restrict__ pairs)
{
    __shared__ int sc[NBUCK];
    __shared__ int hist[NBUCK];
    __shared__ int base[NBUCK];
    const int t = threadIdx.x;

    const int bh = bhist[t];
    sc[t] = bh; __syncthreads();
    for (int off = 1; off < 256; off <<= 1) {
        int v = sc[t];
        if (t >= off) v += sc[t - off];
        __syncthreads(); sc[t] = v; __syncthreads();
    }
    const int bbase = sc[t] - bh;
    hist[t] = 0;
    __syncthreads();

    const int tile0 = blockIdx.x * PC_TILE;
    int sv[PC_EPT], dv[PC_EPT], rk[PC_EPT];
#pragma unroll
    for (int i = 0; i < PC_EPT; ++i) {
        const int e = tile0 + i * 256 + t;
        if (e < E) {
            sv[i] = ei[e];
            dv[i] = ei[E + e];
            rk[i] = atomicAdd(&hist[dv[i] >> 8], 1);
        } else dv[i] = -1;
    }
    __syncthreads();
    if (hist[t] > 0) base[t] = bbase + atomicAdd(&gcurs[t], hist[t]);
    __syncthreads();
#pragma unroll
    for (int i = 0; i < PC_EPT; ++i) {
        if (dv[i] >= 0) {
            const int b = dv[i] >> 8;
            pairs[base[b] + rk[i]] = sv[i] | ((dv[i] & 255) << 16);
        }
    }
}

__global__ __launch_bounds__(256) void fine_scatter(
    const int* __restrict__ bhist, const int* __restrict__ pairs,
    int N, int E, int* __restrict__ row_off, int* __restrict__ csr_src)
{
    __shared__ int sc[NBUCK];
    __shared__ int cnt[NBUCK];
    __shared__ int cur[NBUCK];
    const int t = threadIdx.x, b = blockIdx.x;

    const int bh = bhist[t];
    sc[t] = bh; __syncthreads();
    for (int off = 1; off < 256; off <<= 1) {
        int v = sc[t];
        if (t >= off) v += sc[t - off];
        __syncthreads(); sc[t] = v; __syncthreads();
    }
    sc[t] -= bh;
    cnt[t] = 0;
    __syncthreads();

    const int sb = sc[b];
    const int se = sb + bhist[b];

    for (int p = sb + t; p < se; p += 256)
        atomicAdd(&cnt[pairs[p] >> 16], 1);
    __syncthreads();

    const int c = cnt[t];
    cur[t] = c; __syncthreads();
    for (int off = 1; off < 256; off <<= 1) {
        int v = cur[t];
        if (t >= off) v += cur[t - off];
        __syncthreads(); cur[t] = v; __syncthreads();
    }
    const int node_off = sb + cur[t] - c;
    __syncthreads();
    cur[t] = node_off;
    const int n = b * 256 + t;
    if (n < N) row_off[n] = node_off;
    if (b == gridDim.x - 1 && t == 0) row_off[N] = E;
    __syncthreads();

    for (int p = sb + t; p < se; p += 256) {
        const int v = pairs[p];
        const int pos = atomicAdd(&cur[v >> 16], 1);
        csr_src[pos] = v & 0xFFFF;
    }
}

// ===========================================================================
// GAT aggregation (R8-proven): one wave per dst, no-max softmax
// (shift-invariance, |e| << 88). UNROLL x4: 16 edges in flight per wave,
// 256B gathers (16 lanes x 16B per edge group). One-wave-per-node grid
// (N/4 blocks) keeps device-wide outstanding-request count maximal —
// fusing this into 64-row tiles (R11) collapsed occupancy and regressed.
// ===========================================================================
__global__ __launch_bounds__(256) void gat_aggregate(
    const int* __restrict__ row_off, const int* __restrict__ csr_src,
    const float* __restrict__ h, const float* __restrict__ as,
    const float* __restrict__ ad, const float* __restrict__ bias,
    float* __restrict__ out, int N)
{
    const int wv = (blockIdx.x * 256 + threadIdx.x) >> 6;
    if (wv >= N) return;
    const int d    = wv;
    const int lane = threadIdx.x & 63;
    const int g    = lane >> 4;
    const int gl   = lane & 15;

    const int beg = row_off[d], end = row_off[d + 1];
    const float add = ad[d];

    float  den  = 0.f;
    float4 acc0 = {0.f,0.f,0.f,0.f}, acc1 = {0.f,0.f,0.f,0.f};
    float4 acc2 = {0.f,0.f,0.f,0.f}, acc3 = {0.f,0.f,0.f,0.f};

    // prefetch src indices one 16-edge super-chunk ahead
    int s0 = (beg      + g < end) ? csr_src[beg      + g] : 0;
    int s1 = (beg +  4 + g < end) ? csr_src[beg +  4 + g] : 0;
    int s2 = (beg +  8 + g < end) ? csr_src[beg +  8 + g] : 0;
    int s3 = (beg + 12 + g < end) ? csr_src[beg + 12 + g] : 0;

    for (int e0 = beg; e0 < end; e0 += 16) {
        const bool v0 = (e0      + g < end);
        const bool v1 = (e0 +  4 + g < end);
        const bool v2 = (e0 +  8 + g < end);
        const bool v3 = (e0 + 12 + g < end);
        const int cs0 = s0, cs1 = s1, cs2 = s2, cs3 = s3;

        s0 = (e0 + 16 + g < end) ? csr_src[e0 + 16 + g] : 0;
        s1 = (e0 + 20 + g < end) ? csr_src[e0 + 20 + g] : 0;
        s2 = (e0 + 24 + g < end) ? csr_src[e0 + 24 + g] : 0;
        s3 = (e0 + 28 + g < end) ? csr_src[e0 + 28 + g] : 0;

        // 4 independent gathers + 4 alpha loads issued up front
        const float4 h0 = *(const float4*)&h[(size_t)cs0 * 64 + gl * 4];
        const float4 h1 = *(const float4*)&h[(size_t)cs1 * 64 + gl * 4];
        const float4 h2 = *(const float4*)&h[(size_t)cs2 * 64 + gl * 4];
        const float4 h3 = *(const float4*)&h[(size_t)cs3 * 64 + gl * 4];
        const float  a0 = as[cs0];
        const float  a1 = as[cs1];
        const float  a2 = as[cs2];
        const float  a3 = as[cs3];

        float e0v = a0 + add; e0v = (e0v >= 0.f) ? e0v : NEG_SLOPE * e0v;
        float e1v = a1 + add; e1v = (e1v >= 0.f) ? e1v : NEG_SLOPE * e1v;
        float e2v = a2 + add; e2v = (e2v >= 0.f) ? e2v : NEG_SLOPE * e2v;
        float e3v = a3 + add; e3v = (e3v >= 0.f) ? e3v : NEG_SLOPE * e3v;

        const float w0 = v0 ? __expf(e0v) : 0.f;
        const float w1 = v1 ? __expf(e1v) : 0.f;
        const float w2 = v2 ? __expf(e2v) : 0.f;
        const float w3 = v3 ? __expf(e3v) : 0.f;

        den += (w0 + w1) + (w2 + w3);
        acc0.x += w0 * h0.x; acc0.y += w0 * h0.y;
        acc0.z += w0 * h0.z; acc0.w += w0 * h0.w;
        acc1.x += w1 * h1.x; acc1.y += w1 * h1.y;
        acc1.z += w1 * h1.z; acc1.w += w1 * h1.w;
        acc2.x += w2 * h2.x; acc2.y += w2 * h2.y;
        acc2.z += w2 * h2.z; acc2.w += w2 * h2.w;
        acc3.x += w3 * h3.x; acc3.y += w3 * h3.y;
        acc3.z += w3 * h3.z; acc3.w += w3 * h3.w;
    }

    float4 acc;
    acc.x = (acc0.x + acc1.x) + (acc2.x + acc3.x);
    acc.y = (acc0.y + acc1.y) + (acc2.y + acc3.y);
    acc.z = (acc0.z + acc1.z) + (acc2.z + acc3.z);
    acc.w = (acc0.w + acc1.w) + (acc2.w + acc3.w);

    // reduce the 4 edge-groups (lanes differ in bits 4,5)
#pragma unroll
    for (int off = 16; off <= 32; off <<= 1) {
        acc.x += __shfl_xor(acc.x, off, 64);
        acc.y += __shfl_xor(acc.y, off, 64);
        acc.z += __shfl_xor(acc.z, off, 64);
        acc.w += __shfl_xor(acc.w, off, 64);
        den   += __shfl_xor(den,   off, 64);
    }

    if (g == 0) {
        const float4 bvv = *(const float4*)&bias[gl * 4];
        const float inv = (den > 0.f) ? (1.f / den) : 0.f;
        float4 o;
        o.x = fmaxf(acc.x * inv + bvv.x, 0.f);
        o.y = fmaxf(acc.y * inv + bvv.y, 0.f);
        o.z = fmaxf(acc.z * inv + bvv.z, 0.f);
        o.w = fmaxf(acc.w * inv + bvv.w, 0.f);
        *(float4*)&out[(size_t)d * 64 + gl * 4] = o;
    }
}

extern "C" void kernel_launch(void* const* d_in, const int* in_sizes, int n_in,
                              void* d_out, int out_size, void* d_ws, size_t ws_size,
                              hipStream_t stream)
{
    const float* x  = (const float*)d_in[0];
    const int*   ei = (const int*)d_in[1];
    const float* W[3]    = {(const float*)d_in[2], (const float*)d_in[6],  (const float*)d_in[10]};
    const float* asrc[3] = {(const float*)d_in[3], (const float*)d_in[7],  (const float*)d_in[11]};
    const float* adst[3] = {(const float*)d_in[4], (const float*)d_in[8],  (const float*)d_in[12]};
    const float* bia[3]  = {(const float*)d_in[5], (const float*)d_in[9],  (const float*)d_in[13]};
    const float* lin1W = (const float*)d_in[14];
    const float* lin1b = (const float*)d_in[15];
    const float* lin2W = (const float*)d_in[16];
    const float* lin2b = (const float*)d_in[17];

    const int N = in_sizes[0] / 64;
    const int E = in_sizes[1] / 2;
    const int B = (N + 255) / 256;            // coarse buckets (<=256)

    // workspace layout
    float* X       = (float*)d_ws;            // N*64
    float* H       = X + (size_t)N * 64;      // N*64
    float* AS      = H + (size_t)N * 64;      // N
    float* AD      = AS + N;                  // N
    int*   row_off = (int*)(AD + N);          // N+1
    int*   csr_src = row_off + (N + 1);       // E
    int*   bhist   = csr_src + E;             // 256
    int*   gcurs   = bhist + 256;             // 256
    int*   pairs   = gcurs + 256;             // E

    const int g64_grid = (N + 63) / 64;
    const int agg_grid = (N + 3) / 4;
    const int pc_grid  = (E + PC_TILE - 1) / PC_TILE;

    hipMemsetAsync(bhist, 0, 512 * sizeof(int), stream);

    // ---- layer 1 GEMM (+ fused bucket histogram) ----
    gemm64<true, true><<<g64_grid, 256, 0, stream>>>(
        x, W[0], asrc[0], adst[0], H, AS, AD, N, ei, E, bhist);

    // ---- CSR build ----
    partition_coarse<<<pc_grid, 256, 0, stream>>>(ei, E, bhist, gcurs, pairs);
    fine_scatter<<<B, 256, 0, stream>>>(bhist, pairs, N, E, row_off, csr_src);

    // ---- layer 1 aggregate ----
    gat_aggregate<<<agg_grid, 256, 0, stream>>>(
        row_off, csr_src, H, AS, AD, bia[0], X, N);

    // ---- layers 2,3 ----
    for (int l = 1; l < 3; ++l) {
        gemm64<true, false><<<g64_grid, 256, 0, stream>>>(
            X, W[l], asrc[l], adst[l], H, AS, AD, N, nullptr, 0, nullptr);
        gat_aggregate<<<agg_grid, 256, 0, stream>>>(
            row_off, csr_src, H, AS, AD, bia[l], X, N);
    }

    // ---- fused MLP head ----
    gemm_head<<<g64_grid, 256, 0, stream>>>(
        X, lin1W, lin1b, lin2W, lin2b, (float*)d_out, N);
}